// Round 3
// baseline (1178.414 us; speedup 1.0000x reference)
//
#include <hip/hip_runtime.h>
#include <hip/hip_bf16.h>

#define GNO_T 8

// GELU, tanh approximation (JAX default approximate=True)
__device__ __forceinline__ float gelu_tanh(float x) {
    float u = 0.7978845608028654f * (x + 0.044715f * x * x * x);
    float ex = __expf(2.f * u);
    float th = 1.f - 2.f / (ex + 1.f);   // tanh(u), inf-safe
    return 0.5f * x * (1.f + th);
}

// One block per destination node. 128 threads = 128 latent channels.
// out[x,:] = mean_{e: dst=x} ( (gelu(e_coords @ w1 + b1) @ w2 + b2) * f_y[src_e,:] )
//          [+ add0] [+ add1] [relu]
__global__ __launch_bounds__(128) void gno_kernel(
    const float* __restrict__ coords, int n0, int sx, int sy,
    const float* __restrict__ f_y,
    const int* __restrict__ esrc, const int* __restrict__ edst, int E,
    const float* __restrict__ w1, const float* __restrict__ b1,
    const float* __restrict__ w2, const float* __restrict__ b2,
    const float* __restrict__ add0, const float* __restrict__ add1,
    int do_relu, float* __restrict__ out)
{
    const int b = blockIdx.x;
    const int t = threadIdx.x;

    __shared__ float s_w1[4 * 64];
    __shared__ float s_b1[64];
    __shared__ float s_g[GNO_T * 64];

    if (t < 64) s_b1[t] = b1[t];
    for (int i = t; i < 256; i += 128) s_w1[i] = w1[i];

    // per-thread w2 column in registers (64 VGPRs)
    float w2c[64];
#pragma unroll
    for (int h = 0; h < 64; ++h) w2c[h] = w2[h * 128 + t];
    const float b2c = b2[t];

    // this block's query-point coords
    const float xcx = coords[(long)b * sx];
    const float xcy = coords[n0 + (long)b * sx];

    // segment [lo,hi) of edges with dst == b (edst sorted ascending)
    int lo, hi;
    {
        int l = 0, r = E;
        while (l < r) { int m = (l + r) >> 1; if (edst[m] < b) l = m + 1; else r = m; }
        lo = l; r = E;
        while (l < r) { int m = (l + r) >> 1; if (edst[m] < b + 1) l = m + 1; else r = m; }
        hi = l;
    }

    float acc = 0.f;
    __syncthreads();

    for (int base = lo; base < hi; base += GNO_T) {
        const int cnt = min(GNO_T, hi - base);
        // layer 1: (j,h) work items -> s_g[j][h]
#pragma unroll
        for (int p = 0; p < GNO_T * 64; p += 128) {
            int idx = p + t;
            int j = idx >> 6, h = idx & 63;
            if (j < cnt) {
                int s = esrc[base + j];
                float yx = coords[(long)s * sy];
                float yy = coords[n0 + (long)s * sy];
                float x = yx * s_w1[h] + yy * s_w1[64 + h]
                        + xcx * s_w1[128 + h] + xcy * s_w1[192 + h] + s_b1[h];
                s_g[(j << 6) + h] = gelu_tanh(x);
            }
        }
        __syncthreads();
        // layer 2 + modulate + accumulate
        for (int j = 0; j < cnt; ++j) {
            int s = esrc[base + j];
            float kc = b2c;
#pragma unroll
            for (int h4 = 0; h4 < 64; h4 += 4) {
                float4 g4 = *(const float4*)&s_g[(j << 6) + h4];
                kc += g4.x * w2c[h4] + g4.y * w2c[h4 + 1]
                    + g4.z * w2c[h4 + 2] + g4.w * w2c[h4 + 3];
            }
            acc += kc * f_y[(long)s * 128 + t];
        }
        __syncthreads();
    }

    float res = acc / fmaxf((float)(hi - lo), 1.f);
    if (add0) res += add0[(long)b * 128 + t];
    if (add1) res += add1[(long)b * 128 + t];
    if (do_relu) res = fmaxf(res, 0.f);
    out[(long)b * 128 + t] = res;
}

// out[r,c] = bias[c] + sum_h X[r,h] * W[h,c];  8 rows per block, 128 threads
__global__ __launch_bounds__(128) void matmul128_kernel(
    const float* __restrict__ X, const float* __restrict__ W,
    const float* __restrict__ bias, float* __restrict__ out, int R)
{
    const int r0 = blockIdx.x * 8;
    const int t = threadIdx.x;
    __shared__ float s_x[8 * 128];
#pragma unroll
    for (int j = 0; j < 8; ++j) {
        int r = r0 + j;
        s_x[j * 128 + t] = (r < R) ? X[(long)r * 128 + t] : 0.f;
    }
    __syncthreads();
    float acc[8];
    const float bc = bias[t];
#pragma unroll
    for (int j = 0; j < 8; ++j) acc[j] = bc;
    for (int h = 0; h < 128; ++h) {
        float w = W[h * 128 + t];
#pragma unroll
        for (int j = 0; j < 8; ++j) acc[j] += s_x[j * 128 + h] * w;
    }
#pragma unroll
    for (int j = 0; j < 8; ++j) {
        int r = r0 + j;
        if (r < R) out[(long)r * 128 + t] = acc[j];
    }
}

// v_down0 = samples @ lift_w + lift_b ; one block per node, 128 threads
__global__ __launch_bounds__(128) void lift_kernel(
    const float* __restrict__ samples, const float* __restrict__ W,
    const float* __restrict__ bias, float* __restrict__ out, int N)
{
    const int i = blockIdx.x;
    const int t = threadIdx.x;
    float s0 = samples[i * 3 + 0];
    float s1 = samples[i * 3 + 1];
    float s2 = samples[i * 3 + 2];
    out[(long)i * 128 + t] = s0 * W[t] + s1 * W[128 + t] + s2 * W[256 + t] + bias[t];
}

__global__ void add_relu_kernel(const float* __restrict__ a, const float* __restrict__ b,
                                float* __restrict__ out, int n)
{
    int i = blockIdx.x * blockDim.x + threadIdx.x;
    if (i < n) {
        float v = a[i] + (b ? b[i] : 0.f);
        out[i] = fmaxf(v, 0.f);
    }
}

// out[i,0:3] = V[i,:] @ proj_w + proj_b ; one block (128 thr) per node
__global__ __launch_bounds__(128) void proj_kernel(
    const float* __restrict__ V, const float* __restrict__ Wp,
    const float* __restrict__ bp, float* __restrict__ out, int N)
{
    const int i = blockIdx.x;
    const int t = threadIdx.x;
    float v = V[(long)i * 128 + t];
    float p0 = v * Wp[t * 3 + 0];
    float p1 = v * Wp[t * 3 + 1];
    float p2 = v * Wp[t * 3 + 2];
#pragma unroll
    for (int o = 32; o > 0; o >>= 1) {
        p0 += __shfl_down(p0, o);
        p1 += __shfl_down(p1, o);
        p2 += __shfl_down(p2, o);
    }
    __shared__ float sred[6];
    if ((t & 63) == 0) { int w = t >> 6; sred[w * 3 + 0] = p0; sred[w * 3 + 1] = p1; sred[w * 3 + 2] = p2; }
    __syncthreads();
    if (t < 3) out[i * 3 + t] = sred[t] + sred[3 + t] + bp[t];
}

extern "C" void kernel_launch(void* const* d_in, const int* in_sizes, int n_in,
                              void* d_out, int out_size, void* d_ws, size_t ws_size,
                              hipStream_t stream)
{
    const float* coords  = (const float*)d_in[0];
    const float* samples = (const float*)d_in[1];
    // d_in[2] = sigma (unused by reference)
    const float* lift_w  = (const float*)d_in[3];
    const float* lift_b  = (const float*)d_in[4];
    const float* proj_w  = (const float*)d_in[5];
    const float* proj_b  = (const float*)d_in[6];
    const float* W0_w    = (const float*)d_in[7];
    const float* W0_b    = (const float*)d_in[8];
    const float* W1_w    = (const float*)d_in[9];
    const float* W1_b    = (const float*)d_in[10];
    // gk order: 0=gk00, 1=gk01, 2=gk10, 3=gk11
    const float *gw1[4], *gb1[4], *gw2[4], *gb2[4];
    for (int g = 0; g < 4; ++g) {
        gw1[g] = (const float*)d_in[11 + 4 * g + 0];
        gb1[g] = (const float*)d_in[11 + 4 * g + 1];
        gw2[g] = (const float*)d_in[11 + 4 * g + 2];
        gb2[g] = (const float*)d_in[11 + 4 * g + 3];
    }
    const int* es[4]; const int* ed[4]; int E[4];
    for (int g = 0; g < 4; ++g) {
        es[g] = (const int*)d_in[27 + 2 * g];
        ed[g] = (const int*)d_in[27 + 2 * g + 1];
        E[g]  = in_sizes[27 + 2 * g];
    }

    const int N0 = in_sizes[0] / 2;     // 8192
    const int N1 = (N0 + 1) / 2;        // 4096

    float* ws = (float*)d_ws;
    float* v_down0 = ws;                              // N0*128
    float* w0term  = v_down0 + (size_t)N0 * 128;      // N0*128
    float* gno00o  = w0term  + (size_t)N0 * 128;      // N0*128
    float* v_up0   = gno00o  + (size_t)N0 * 128;      // N0*128
    float* gno01b  = v_up0   + (size_t)N0 * 128;      // N1*128
    float* v_down1 = gno01b  + (size_t)N1 * 128;      // N1*128
    float* w1term  = v_down1 + (size_t)N1 * 128;      // N1*128
    float* v_up1   = w1term  + (size_t)N1 * 128;      // N1*128

    // loop-invariant precomputation:
    //  - edge-kernel MLPs depend only on coords (constant across iterations)
    //  - v_down0 never changes => gno00, gno01-base, v_down0@W0 computed once
    //  - v_up0 only needed after the last iteration => gno10 computed once
    lift_kernel<<<N0, 128, 0, stream>>>(samples, lift_w, lift_b, v_down0, N0);
    matmul128_kernel<<<(N0 + 7) / 8, 128, 0, stream>>>(v_down0, W0_w, W0_b, w0term, N0);
    // gno00: x=lvl0 (sx=1), y=lvl0 (sy=1), f=v_down0
    gno_kernel<<<N0, 128, 0, stream>>>(coords, N0, 1, 1, v_down0,
        es[0], ed[0], E[0], gw1[0], gb1[0], gw2[0], gb2[0],
        nullptr, nullptr, 0, gno00o);
    // gno01 base: x=lvl1 (sx=2), y=lvl0 (sy=1), f=v_down0
    gno_kernel<<<N1, 128, 0, stream>>>(coords, N0, 2, 1, v_down0,
        es[1], ed[1], E[1], gw1[1], gb1[1], gw2[1], gb2[1],
        nullptr, nullptr, 0, gno01b);

    // 3 iterations of the coarse-level recursion
    for (int it = 0; it < 3; ++it) {
        add_relu_kernel<<<(N1 * 128 + 255) / 256, 256, 0, stream>>>(
            gno01b, (it == 0) ? nullptr : v_up1, v_down1, N1 * 128);
        matmul128_kernel<<<(N1 + 7) / 8, 128, 0, stream>>>(v_down1, W1_w, W1_b, w1term, N1);
        // gno11: x=lvl1, y=lvl1, f=v_down1; v_up1 = relu(mean + w1term)
        gno_kernel<<<N1, 128, 0, stream>>>(coords, N0, 2, 2, v_down1,
            es[3], ed[3], E[3], gw1[3], gb1[3], gw2[3], gb2[3],
            w1term, nullptr, 1, v_up1);
    }

    // final upward pass
    // gno10: x=lvl0, y=lvl1, f=v_up1; v_up0 = relu(mean + w0term + gno00o)
    gno_kernel<<<N0, 128, 0, stream>>>(coords, N0, 1, 2, v_up1,
        es[2], ed[2], E[2], gw1[2], gb1[2], gw2[2], gb2[2],
        w0term, gno00o, 1, v_up0);

    proj_kernel<<<N0, 128, 0, stream>>>(v_up0, proj_w, proj_b, (float*)d_out, N0);
}

// Round 4
// 524.874 us; speedup vs baseline: 2.2451x; 2.2451x over previous
//
#include <hip/hip_runtime.h>
#include <hip/hip_bf16.h>

typedef __attribute__((ext_vector_type(8))) short s8;   // 8 bf16 = 4 VGPRs
typedef __attribute__((ext_vector_type(4))) float f4;

// GELU, tanh approximation (JAX default approximate=True)
__device__ __forceinline__ float gelu_tanh(float x) {
    float u = 0.7978845608028654f * (x + 0.044715f * x * x * x);
    float ex = __expf(2.f * u);
    float th = 1.f - 2.f / (ex + 1.f);   // tanh(u), inf-safe
    return 0.5f * x * (1.f + th);
}

__device__ __forceinline__ short f2bf_bits(float v) {
    __hip_bfloat16 b = __float2bfloat16(v);
    return *(short*)&b;
}

// Pack w2 (64x128 f32, row-major [h][c]) into MFMA B-fragment order, bf16.
// Fragment group g = ((w*4+T)*2+s), lane holds 8 bf16: k = s*32+q*8+j, ch = 64w+16T+n.
// Layout: out[(g*64 + lane)*8 + j]  -> per (T,s) the wave reads 1 KB coalesced.
__global__ __launch_bounds__(128) void pack_w2_kernel(
    const float* __restrict__ w2, short* __restrict__ out)
{
    const int t = threadIdx.x;
    const int w = t >> 6, lane = t & 63, q = lane >> 4, n = lane & 15;
#pragma unroll
    for (int T = 0; T < 4; ++T)
#pragma unroll
        for (int s = 0; s < 2; ++s)
#pragma unroll
            for (int j = 0; j < 8; ++j) {
                int k  = s * 32 + q * 8 + j;
                int ch = 64 * w + 16 * T + n;
                out[((((w * 4 + T) * 2 + s) * 64) + lane) * 8 + j] =
                    f2bf_bits(w2[k * 128 + ch]);
            }
}

// One block per destination node, 128 threads (2 waves, 64 channels each).
// Edges in groups of 16; layer1 (coords->gelu hidden) in f32 VALU -> bf16 LDS,
// layer2 (hidden @ w2) on MFMA 16x16x32_bf16, modulate by f_y[src], scatter-mean.
__global__ __launch_bounds__(128) void gno_kernel(
    const float* __restrict__ coords, int n0, int sx, int sy,
    const float* __restrict__ f_y,
    const int* __restrict__ esrc, const int* __restrict__ edst, int E,
    const float* __restrict__ w1, const float* __restrict__ b1,
    const short* __restrict__ w2bf, const float* __restrict__ b2,
    const float* __restrict__ add0, const float* __restrict__ add1,
    int do_relu, float* __restrict__ out)
{
    const int b = blockIdx.x, t = threadIdx.x;
    const int w = t >> 6, lane = t & 63, q = lane >> 4, n = lane & 15;

    __shared__ float s_w1[256];
    __shared__ float s_b1[64];
    __shared__ __align__(16) short s_gb[16 * 72];   // 16 edges x 64 hidden, stride 72 (bank-friendly)
    __shared__ int   s_src[2][16];
    __shared__ float s_yx[2][16], s_yy[2][16];

    if (t < 64) s_b1[t] = b1[t];
    for (int i = t; i < 256; i += 128) s_w1[i] = w1[i];

    // B fragments (constant): 4 col-tiles x 2 K-steps, preconverted bf16
    s8 bfrag[4][2];
    const s8* w2f = (const s8*)w2bf;
#pragma unroll
    for (int T = 0; T < 4; ++T)
#pragma unroll
        for (int s = 0; s < 2; ++s)
            bfrag[T][s] = w2f[((w * 4 + T) * 2 + s) * 64 + lane];

    float b2c[4];
#pragma unroll
    for (int T = 0; T < 4; ++T) b2c[T] = b2[w * 64 + T * 16 + n];

    const float xcx = coords[(long)b * sx];
    const float xcy = coords[n0 + (long)b * sx];

    // segment [lo,hi) of edges with dst == b (edst sorted ascending)
    int lo, hi;
    {
        int l = 0, r = E;
        while (l < r) { int m = (l + r) >> 1; if (edst[m] < b) l = m + 1; else r = m; }
        lo = l; r = E;
        while (l < r) { int m = (l + r) >> 1; if (edst[m] < b + 1) l = m + 1; else r = m; }
        hi = l;
    }

    float acc4[4] = {0.f, 0.f, 0.f, 0.f};
    __syncthreads();   // s_w1/s_b1 visible

    int gi = 0;
    for (int base = lo; base < hi; base += 16, ++gi) {
        const int buf = gi & 1;
        const int cnt = min(16, hi - base);
        // stage sources for this group
        if (t < 16) {
            int e = base + t; if (e >= hi) e = hi - 1;
            int sv = esrc[e];
            s_src[buf][t] = sv;
            s_yx[buf][t]  = coords[(long)sv * sy];
            s_yy[buf][t]  = coords[n0 + (long)sv * sy];
        }
        __syncthreads();
        // layer1: 16 edges x 64 hidden -> bf16 in s_gb (A-operand row-major, stride 72)
#pragma unroll
        for (int p = 0; p < 1024; p += 128) {
            int idx = p + t, j = idx >> 6, h = idx & 63;
            float yx = s_yx[buf][j], yy = s_yy[buf][j];
            float x = yx * s_w1[h] + yy * s_w1[64 + h]
                    + xcx * s_w1[128 + h] + xcy * s_w1[192 + h] + s_b1[h];
            s_gb[j * 72 + h] = f2bf_bits(gelu_tanh(x));
        }
        __syncthreads();
        // layer2: k-tile = g @ w2 via MFMA. A: m=lane&15 (edge), k=q*8+j.
        const s8 a0 = *(const s8*)&s_gb[n * 72 + q * 8];
        const s8 a1 = *(const s8*)&s_gb[n * 72 + q * 8 + 32];
        f4 c[4];
#pragma unroll
        for (int T = 0; T < 4; ++T) {
            f4 z = {0.f, 0.f, 0.f, 0.f};
            z = __builtin_amdgcn_mfma_f32_16x16x32_bf16(a0, bfrag[T][0], z, 0, 0, 0);
            c[T] = __builtin_amdgcn_mfma_f32_16x16x32_bf16(a1, bfrag[T][1], z, 0, 0, 0);
        }
        // modulate by f_y[src] and accumulate (padded rows multiply by 0)
#pragma unroll
        for (int r = 0; r < 4; ++r) {
            int m = q * 4 + r;
            bool valid = m < cnt;
            long srow = (long)s_src[buf][m] * 128;
#pragma unroll
            for (int T = 0; T < 4; ++T) {
                float fv = valid ? f_y[srow + w * 64 + T * 16 + n] : 0.f;
                acc4[T] += (c[T][r] + b2c[T]) * fv;
            }
        }
    }

    // reduce over the 4 quads (edge-row partitions), epilogue
    const float inv = 1.f / fmaxf((float)(hi - lo), 1.f);
#pragma unroll
    for (int T = 0; T < 4; ++T) {
        float v = acc4[T];
        v += __shfl_xor(v, 16, 64);
        v += __shfl_xor(v, 32, 64);
        if (q == 0) {
            int ch = w * 64 + T * 16 + n;
            long o = (long)b * 128 + ch;
            float res = v * inv;
            if (add0) res += add0[o];
            if (add1) res += add1[o];
            if (do_relu) res = fmaxf(res, 0.f);
            out[o] = res;
        }
    }
}

// out[r,c] = bias[c] + sum_h X[r,h] * W[h,c];  8 rows per block, 128 threads
__global__ __launch_bounds__(128) void matmul128_kernel(
    const float* __restrict__ X, const float* __restrict__ W,
    const float* __restrict__ bias, float* __restrict__ out, int R)
{
    const int r0 = blockIdx.x * 8;
    const int t = threadIdx.x;
    __shared__ float s_x[8 * 128];
#pragma unroll
    for (int j = 0; j < 8; ++j) {
        int r = r0 + j;
        s_x[j * 128 + t] = (r < R) ? X[(long)r * 128 + t] : 0.f;
    }
    __syncthreads();
    float acc[8];
    const float bc = bias[t];
#pragma unroll
    for (int j = 0; j < 8; ++j) acc[j] = bc;
    for (int h = 0; h < 128; ++h) {
        float w = W[h * 128 + t];
#pragma unroll
        for (int j = 0; j < 8; ++j) acc[j] += s_x[j * 128 + h] * w;
    }
#pragma unroll
    for (int j = 0; j < 8; ++j) {
        int r = r0 + j;
        if (r < R) out[(long)r * 128 + t] = acc[j];
    }
}

// v_down0 = samples @ lift_w + lift_b ; one block per node, 128 threads
__global__ __launch_bounds__(128) void lift_kernel(
    const float* __restrict__ samples, const float* __restrict__ W,
    const float* __restrict__ bias, float* __restrict__ out, int N)
{
    const int i = blockIdx.x;
    const int t = threadIdx.x;
    float s0 = samples[i * 3 + 0];
    float s1 = samples[i * 3 + 1];
    float s2 = samples[i * 3 + 2];
    out[(long)i * 128 + t] = s0 * W[t] + s1 * W[128 + t] + s2 * W[256 + t] + bias[t];
}

__global__ void add_relu_kernel(const float* __restrict__ a, const float* __restrict__ b,
                                float* __restrict__ out, int n)
{
    int i = blockIdx.x * blockDim.x + threadIdx.x;
    if (i < n) {
        float v = a[i] + (b ? b[i] : 0.f);
        out[i] = fmaxf(v, 0.f);
    }
}

// out[i,0:3] = V[i,:] @ proj_w + proj_b ; one block (128 thr) per node
__global__ __launch_bounds__(128) void proj_kernel(
    const float* __restrict__ V, const float* __restrict__ Wp,
    const float* __restrict__ bp, float* __restrict__ out, int N)
{
    const int i = blockIdx.x;
    const int t = threadIdx.x;
    float v = V[(long)i * 128 + t];
    float p0 = v * Wp[t * 3 + 0];
    float p1 = v * Wp[t * 3 + 1];
    float p2 = v * Wp[t * 3 + 2];
#pragma unroll
    for (int o = 32; o > 0; o >>= 1) {
        p0 += __shfl_down(p0, o);
        p1 += __shfl_down(p1, o);
        p2 += __shfl_down(p2, o);
    }
    __shared__ float sred[6];
    if ((t & 63) == 0) { int w = t >> 6; sred[w * 3 + 0] = p0; sred[w * 3 + 1] = p1; sred[w * 3 + 2] = p2; }
    __syncthreads();
    if (t < 3) out[i * 3 + t] = sred[t] + sred[3 + t] + bp[t];
}

extern "C" void kernel_launch(void* const* d_in, const int* in_sizes, int n_in,
                              void* d_out, int out_size, void* d_ws, size_t ws_size,
                              hipStream_t stream)
{
    const float* coords  = (const float*)d_in[0];
    const float* samples = (const float*)d_in[1];
    // d_in[2] = sigma (unused by reference)
    const float* lift_w  = (const float*)d_in[3];
    const float* lift_b  = (const float*)d_in[4];
    const float* proj_w  = (const float*)d_in[5];
    const float* proj_b  = (const float*)d_in[6];
    const float* W0_w    = (const float*)d_in[7];
    const float* W0_b    = (const float*)d_in[8];
    const float* W1_w    = (const float*)d_in[9];
    const float* W1_b    = (const float*)d_in[10];
    // gk order: 0=gk00, 1=gk01, 2=gk10, 3=gk11
    const float *gw1[4], *gb1[4], *gw2[4], *gb2[4];
    for (int g = 0; g < 4; ++g) {
        gw1[g] = (const float*)d_in[11 + 4 * g + 0];
        gb1[g] = (const float*)d_in[11 + 4 * g + 1];
        gw2[g] = (const float*)d_in[11 + 4 * g + 2];
        gb2[g] = (const float*)d_in[11 + 4 * g + 3];
    }
    const int* es[4]; const int* ed[4]; int E[4];
    for (int g = 0; g < 4; ++g) {
        es[g] = (const int*)d_in[27 + 2 * g];
        ed[g] = (const int*)d_in[27 + 2 * g + 1];
        E[g]  = in_sizes[27 + 2 * g];
    }

    const int N0 = in_sizes[0] / 2;     // 8192
    const int N1 = (N0 + 1) / 2;        // 4096

    float* ws = (float*)d_ws;
    float* v_down0 = ws;                              // N0*128
    float* w0term  = v_down0 + (size_t)N0 * 128;      // N0*128
    float* gno00o  = w0term  + (size_t)N0 * 128;      // N0*128
    float* v_up0   = gno00o  + (size_t)N0 * 128;      // N0*128
    float* gno01b  = v_up0   + (size_t)N0 * 128;      // N1*128
    float* v_down1 = gno01b  + (size_t)N1 * 128;      // N1*128
    float* w1term  = v_down1 + (size_t)N1 * 128;      // N1*128
    float* v_up1   = w1term  + (size_t)N1 * 128;      // N1*128
    short* w2pack  = (short*)(v_up1 + (size_t)N1 * 128);  // 4 * 8192 bf16

    // one-time weight packing into MFMA B-fragment layout
    for (int g = 0; g < 4; ++g)
        pack_w2_kernel<<<1, 128, 0, stream>>>(gw2[g], w2pack + (size_t)g * 8192);

    // loop-invariant precomputation:
    //  - edge-kernel MLPs depend only on coords (constant across iterations)
    //  - v_down0 never changes => gno00, gno01-base, v_down0@W0 computed once
    //  - v_up0 only needed after the last iteration => gno10 computed once
    lift_kernel<<<N0, 128, 0, stream>>>(samples, lift_w, lift_b, v_down0, N0);
    matmul128_kernel<<<(N0 + 7) / 8, 128, 0, stream>>>(v_down0, W0_w, W0_b, w0term, N0);
    // gno00: x=lvl0 (sx=1), y=lvl0 (sy=1), f=v_down0
    gno_kernel<<<N0, 128, 0, stream>>>(coords, N0, 1, 1, v_down0,
        es[0], ed[0], E[0], gw1[0], gb1[0], w2pack + 0 * 8192, gb2[0],
        nullptr, nullptr, 0, gno00o);
    // gno01 base: x=lvl1 (sx=2), y=lvl0 (sy=1), f=v_down0
    gno_kernel<<<N1, 128, 0, stream>>>(coords, N0, 2, 1, v_down0,
        es[1], ed[1], E[1], gw1[1], gb1[1], w2pack + 1 * 8192, gb2[1],
        nullptr, nullptr, 0, gno01b);

    // 3 iterations of the coarse-level recursion
    for (int it = 0; it < 3; ++it) {
        add_relu_kernel<<<(N1 * 128 + 255) / 256, 256, 0, stream>>>(
            gno01b, (it == 0) ? nullptr : v_up1, v_down1, N1 * 128);
        matmul128_kernel<<<(N1 + 7) / 8, 128, 0, stream>>>(v_down1, W1_w, W1_b, w1term, N1);
        // gno11: x=lvl1, y=lvl1, f=v_down1; v_up1 = relu(mean + w1term)
        gno_kernel<<<N1, 128, 0, stream>>>(coords, N0, 2, 2, v_down1,
            es[3], ed[3], E[3], gw1[3], gb1[3], w2pack + 3 * 8192, gb2[3],
            w1term, nullptr, 1, v_up1);
    }

    // final upward pass
    // gno10: x=lvl0, y=lvl1, f=v_up1; v_up0 = relu(mean + w0term + gno00o)
    gno_kernel<<<N0, 128, 0, stream>>>(coords, N0, 1, 2, v_up1,
        es[2], ed[2], E[2], gw1[2], gb1[2], w2pack + 2 * 8192, gb2[2],
        w0term, gno00o, 1, v_up0);

    proj_kernel<<<N0, 128, 0, stream>>>(v_up0, proj_w, proj_b, (float*)d_out, N0);
}

// Round 5
// 368.473 us; speedup vs baseline: 3.1981x; 1.4245x over previous
//
#include <hip/hip_runtime.h>
#include <hip/hip_bf16.h>

typedef __attribute__((ext_vector_type(8))) short s8;   // 8 bf16 = 4 VGPRs
typedef __attribute__((ext_vector_type(4))) float f4;

// gelu tanh-approx (JAX approximate=True), algebraically reduced:
// gelu(x) = 0.5x(1+tanh(u)) = x * (1 - 1/(exp(2u)+1)),  2u = x*(1.59576912 + 0.07135482 x^2)
__device__ __forceinline__ float gelu_fast(float x) {
    float x2 = x * x;
    float k  = x * fmaf(x2, 0.07135481624f, 1.59576912161f);
    float e  = __expf(k);
    float r  = __builtin_amdgcn_rcpf(e + 1.f);
    return x - x * r;
}

__device__ __forceinline__ short f2bf_bits(float v) {
    __hip_bfloat16 b = __float2bfloat16(v);
    return *(short*)&b;
}

struct RP { const int* edst; int E; int N; int* rowptr; };

// Build CSR row pointers for all 4 graphs (edst sorted ascending).
__global__ void rowptr4_kernel(RP a, RP b, RP c, RP d) {
    RP g = (blockIdx.y == 0) ? a : (blockIdx.y == 1) ? b : (blockIdx.y == 2) ? c : d;
    int i = blockIdx.x * blockDim.x + threadIdx.x;
    if (i >= g.E) return;
    int dd = g.edst[i];
    int p  = (i == 0) ? -1 : g.edst[i - 1];
    for (int r = p + 1; r <= dd; ++r) g.rowptr[r] = i;
    if (i == g.E - 1)
        for (int r = dd + 1; r <= g.N; ++r) g.rowptr[r] = g.E;
}

// Pack w2 (64x128 f32, row-major [k][ch]) into MFMA B-fragment order, bf16.
// group g = ((w*4+T)*2+s); lane holds 8 bf16: k = s*32+q*8+j, ch = 64w+16T+n.
__global__ __launch_bounds__(128) void pack_w2_kernel(
    const float* __restrict__ wa, const float* __restrict__ wb,
    const float* __restrict__ wc, const float* __restrict__ wd,
    short* __restrict__ out)
{
    const float* w2 = (blockIdx.x == 0) ? wa : (blockIdx.x == 1) ? wb
                    : (blockIdx.x == 2) ? wc : wd;
    short* dst = out + (size_t)blockIdx.x * 8192;
    const int t = threadIdx.x;
    const int w = t >> 6, lane = t & 63, q = (lane >> 4), n = lane & 15;
#pragma unroll
    for (int T = 0; T < 4; ++T)
#pragma unroll
        for (int s = 0; s < 2; ++s)
#pragma unroll
            for (int j = 0; j < 8; ++j) {
                int k  = s * 32 + q * 8 + j;
                int ch = 64 * w + 16 * T + n;
                dst[((((w * 4 + T) * 2 + s) * 64) + lane) * 8 + j] =
                    f2bf_bits(w2[k * 128 + ch]);
            }
}

// One block per destination node, 128 threads (2 waves, 64 channels each).
// Edges in groups of 16; layer1 f32 VALU -> bf16 LDS; layer2 on MFMA 16x16x32_bf16;
// modulate by prefetched f_y[src]; scatter-mean; optional fused projection epilogue.
__global__ __launch_bounds__(128) void gno_kernel(
    const float* __restrict__ coords, int n0, int sx, int sy,
    const float* __restrict__ f_y,
    const int* __restrict__ esrc, const int* __restrict__ rowptr,
    const float* __restrict__ w1, const float* __restrict__ b1,
    const short* __restrict__ w2bf, const float* __restrict__ b2,
    const float* __restrict__ add0, const float* __restrict__ add1,
    int do_relu, float* __restrict__ out,
    const float* __restrict__ projw, const float* __restrict__ projb,
    float* __restrict__ fout)
{
    const int b = blockIdx.x, t = threadIdx.x;
    const int w = t >> 6, lane = t & 63, q = lane >> 4, n = lane & 15;
    const int h = lane;   // layer-1 hidden index (thread-constant)

    __shared__ int   s_src[16];
    __shared__ float s_yx[16], s_yy[16];
    __shared__ __align__(16) short s_gb[16 * 72];   // 16 edges x 64 hidden, stride 72
    __shared__ float sred[6];

    // thread-resident layer-1 weights; query-coord contribution folded in
    const float rw0 = w1[h], rw1 = w1[64 + h];
    const float xcx = coords[(long)b * sx];
    const float xcy = coords[n0 + (long)b * sx];
    const float xcc = xcx * w1[128 + h] + xcy * w1[192 + h] + b1[h];

    // B fragments (constant): 4 col-tiles x 2 K-steps, prepacked bf16
    s8 bfrag[4][2];
    const s8* w2f = (const s8*)w2bf;
#pragma unroll
    for (int T = 0; T < 4; ++T)
#pragma unroll
        for (int s = 0; s < 2; ++s)
            bfrag[T][s] = w2f[((w * 4 + T) * 2 + s) * 64 + lane];

    float b2c[4];
#pragma unroll
    for (int T = 0; T < 4; ++T) b2c[T] = b2[w * 64 + T * 16 + n];

    const int lo = rowptr[b], hi = rowptr[b + 1];

    float acc4[4] = {0.f, 0.f, 0.f, 0.f};

    for (int base = lo; base < hi; base += 16) {
        const int cnt = min(16, hi - base);
        if (t < 16) {
            int e = base + t; if (e >= hi) e = hi - 1;
            int sv = esrc[e];
            s_src[t] = sv;
            s_yx[t]  = coords[(long)sv * sy];
            s_yy[t]  = coords[n0 + (long)sv * sy];
        }
        __syncthreads();
        // prefetch f_y gather (latency overlapped with layer1 + MFMA below)
        float fv[4][4];
#pragma unroll
        for (int r = 0; r < 4; ++r) {
            int m = q * 4 + r;
            bool valid = m < cnt;
            long srow = (long)s_src[m] * 128;
#pragma unroll
            for (int T = 0; T < 4; ++T)
                fv[r][T] = valid ? f_y[srow + w * 64 + T * 16 + n] : 0.f;
        }
        // layer1: edge j = 2*i + w, hidden h
#pragma unroll
        for (int i = 0; i < 8; ++i) {
            int j = 2 * i + w;
            float x = fmaf(s_yx[j], rw0, fmaf(s_yy[j], rw1, xcc));
            s_gb[j * 72 + h] = f2bf_bits(gelu_fast(x));
        }
        __syncthreads();
        // layer2 MFMA: A m=edge (lane&15), k=q*8+j
        const s8 a0 = *(const s8*)&s_gb[n * 72 + q * 8];
        const s8 a1 = *(const s8*)&s_gb[n * 72 + q * 8 + 32];
        f4 c[4];
#pragma unroll
        for (int T = 0; T < 4; ++T) {
            f4 z = {0.f, 0.f, 0.f, 0.f};
            z = __builtin_amdgcn_mfma_f32_16x16x32_bf16(a0, bfrag[T][0], z, 0, 0, 0);
            c[T] = __builtin_amdgcn_mfma_f32_16x16x32_bf16(a1, bfrag[T][1], z, 0, 0, 0);
        }
#pragma unroll
        for (int r = 0; r < 4; ++r)
#pragma unroll
            for (int T = 0; T < 4; ++T)
                acc4[T] += (c[T][r] + b2c[T]) * fv[r][T];
    }

    // reduce over the 4 quads (edge-row partitions), epilogue
    const float inv = 1.f / fmaxf((float)(hi - lo), 1.f);
    float res4[4];
#pragma unroll
    for (int T = 0; T < 4; ++T) {
        float v = acc4[T];
        v += __shfl_xor(v, 16, 64);
        v += __shfl_xor(v, 32, 64);
        long o = (long)b * 128 + w * 64 + T * 16 + n;
        float res = v * inv;
        if (add0) res += add0[o];
        if (add1) res += add1[o];
        if (do_relu) res = fmaxf(res, 0.f);
        res4[T] = res;
    }
    if (!projw) {
        if (q == 0)
#pragma unroll
            for (int T = 0; T < 4; ++T)
                out[(long)b * 128 + w * 64 + T * 16 + n] = res4[T];
    } else {
        // fused projection: out[b,0:3] = res @ projw + projb
        __syncthreads();
        float* s_pr = (float*)s_gb;
        if (q == 0)
#pragma unroll
            for (int T = 0; T < 4; ++T) s_pr[w * 64 + T * 16 + n] = res4[T];
        __syncthreads();
        float v = s_pr[t];
        float p0 = v * projw[t * 3 + 0];
        float p1 = v * projw[t * 3 + 1];
        float p2 = v * projw[t * 3 + 2];
#pragma unroll
        for (int o = 32; o > 0; o >>= 1) {
            p0 += __shfl_down(p0, o);
            p1 += __shfl_down(p1, o);
            p2 += __shfl_down(p2, o);
        }
        if (lane == 0) { sred[w * 3 + 0] = p0; sred[w * 3 + 1] = p1; sred[w * 3 + 2] = p2; }
        __syncthreads();
        if (t < 3) fout[b * 3 + t] = sred[t] + sred[3 + t] + projb[t];
    }
}

// v_down1 = relu(base + addl); w1out[r,c] = bias[c] + sum_h v_down1[r,h]*W[h,c]
__global__ __launch_bounds__(128) void fused_relu_mm_kernel(
    const float* __restrict__ base, const float* __restrict__ addl,
    float* __restrict__ vout,
    const float* __restrict__ W, const float* __restrict__ bias,
    float* __restrict__ out, int R)
{
    const int r0 = blockIdx.x * 8;
    const int t = threadIdx.x;
    __shared__ float s_x[8 * 128];
#pragma unroll
    for (int j = 0; j < 8; ++j) {
        int r = r0 + j;
        if (r < R) {
            long o = (long)r * 128 + t;
            float v = base[o] + (addl ? addl[o] : 0.f);
            v = fmaxf(v, 0.f);
            s_x[j * 128 + t] = v;
            vout[o] = v;
        } else s_x[j * 128 + t] = 0.f;
    }
    __syncthreads();
    float acc[8];
    const float bc = bias[t];
#pragma unroll
    for (int j = 0; j < 8; ++j) acc[j] = bc;
    for (int hh = 0; hh < 128; ++hh) {
        float wv = W[hh * 128 + t];
#pragma unroll
        for (int j = 0; j < 8; ++j) acc[j] += s_x[j * 128 + hh] * wv;
    }
#pragma unroll
    for (int j = 0; j < 8; ++j) {
        int r = r0 + j;
        if (r < R) out[(long)r * 128 + t] = acc[j];
    }
}

// plain matmul (for W0 term): out = X @ W + bias
__global__ __launch_bounds__(128) void matmul128_kernel(
    const float* __restrict__ X, const float* __restrict__ W,
    const float* __restrict__ bias, float* __restrict__ out, int R)
{
    const int r0 = blockIdx.x * 8;
    const int t = threadIdx.x;
    __shared__ float s_x[8 * 128];
#pragma unroll
    for (int j = 0; j < 8; ++j) {
        int r = r0 + j;
        s_x[j * 128 + t] = (r < R) ? X[(long)r * 128 + t] : 0.f;
    }
    __syncthreads();
    float acc[8];
    const float bc = bias[t];
#pragma unroll
    for (int j = 0; j < 8; ++j) acc[j] = bc;
    for (int hh = 0; hh < 128; ++hh) {
        float wv = W[hh * 128 + t];
#pragma unroll
        for (int j = 0; j < 8; ++j) acc[j] += s_x[j * 128 + hh] * wv;
    }
#pragma unroll
    for (int j = 0; j < 8; ++j) {
        int r = r0 + j;
        if (r < R) out[(long)r * 128 + t] = acc[j];
    }
}

// v_down0 = samples @ lift_w + lift_b ; one block per node, 128 threads
__global__ __launch_bounds__(128) void lift_kernel(
    const float* __restrict__ samples, const float* __restrict__ W,
    const float* __restrict__ bias, float* __restrict__ out, int N)
{
    const int i = blockIdx.x;
    const int t = threadIdx.x;
    float s0 = samples[i * 3 + 0];
    float s1 = samples[i * 3 + 1];
    float s2 = samples[i * 3 + 2];
    out[(long)i * 128 + t] = s0 * W[t] + s1 * W[128 + t] + s2 * W[256 + t] + bias[t];
}

extern "C" void kernel_launch(void* const* d_in, const int* in_sizes, int n_in,
                              void* d_out, int out_size, void* d_ws, size_t ws_size,
                              hipStream_t stream)
{
    const float* coords  = (const float*)d_in[0];
    const float* samples = (const float*)d_in[1];
    // d_in[2] = sigma (unused)
    const float* lift_w  = (const float*)d_in[3];
    const float* lift_b  = (const float*)d_in[4];
    const float* proj_w  = (const float*)d_in[5];
    const float* proj_b  = (const float*)d_in[6];
    const float* W0_w    = (const float*)d_in[7];
    const float* W0_b    = (const float*)d_in[8];
    const float* W1_w    = (const float*)d_in[9];
    const float* W1_b    = (const float*)d_in[10];
    const float *gw1[4], *gb1[4], *gw2[4], *gb2[4];   // 0=gk00,1=gk01,2=gk10,3=gk11
    for (int g = 0; g < 4; ++g) {
        gw1[g] = (const float*)d_in[11 + 4 * g + 0];
        gb1[g] = (const float*)d_in[11 + 4 * g + 1];
        gw2[g] = (const float*)d_in[11 + 4 * g + 2];
        gb2[g] = (const float*)d_in[11 + 4 * g + 3];
    }
    const int* es[4]; const int* ed[4]; int E[4];
    for (int g = 0; g < 4; ++g) {
        es[g] = (const int*)d_in[27 + 2 * g];
        ed[g] = (const int*)d_in[27 + 2 * g + 1];
        E[g]  = in_sizes[27 + 2 * g];
    }

    const int N0 = in_sizes[0] / 2;     // 8192
    const int N1 = (N0 + 1) / 2;        // 4096

    float* ws = (float*)d_ws;
    float* v_down0 = ws;                              // N0*128
    float* w0term  = v_down0 + (size_t)N0 * 128;      // N0*128
    float* gno00o  = w0term  + (size_t)N0 * 128;      // N0*128
    float* gno01b  = gno00o  + (size_t)N0 * 128;      // N1*128
    float* v_down1 = gno01b  + (size_t)N1 * 128;      // N1*128
    float* w1term  = v_down1 + (size_t)N1 * 128;      // N1*128
    float* v_up1   = w1term  + (size_t)N1 * 128;      // N1*128
    short* w2pack  = (short*)(v_up1 + (size_t)N1 * 128);  // 4*8192 bf16
    int*   rp      = (int*)(w2pack + 4 * 8192);
    int* rp00 = rp;                // N0+1 (dst in lvl0)
    int* rp01 = rp00 + (N0 + 1);   // N1+1 (dst in lvl1)
    int* rp10 = rp01 + (N1 + 1);   // N0+1
    int* rp11 = rp10 + (N0 + 1);   // N1+1
    int* rptr[4] = {rp00, rp01, rp10, rp11};
    int  rpN[4]  = {N0, N1, N0, N1};

    // CSR row pointers for all 4 graphs (kills per-block binary search)
    {
        int maxE = E[0];
        for (int g = 1; g < 4; ++g) maxE = max(maxE, E[g]);
        RP a = {ed[0], E[0], rpN[0], rptr[0]};
        RP b = {ed[1], E[1], rpN[1], rptr[1]};
        RP c = {ed[2], E[2], rpN[2], rptr[2]};
        RP d = {ed[3], E[3], rpN[3], rptr[3]};
        dim3 grid((maxE + 255) / 256, 4);
        rowptr4_kernel<<<grid, 256, 0, stream>>>(a, b, c, d);
    }
    // one-time weight packing into MFMA B-fragment layout (4 blocks, one per graph)
    pack_w2_kernel<<<4, 128, 0, stream>>>(gw2[0], gw2[1], gw2[2], gw2[3], w2pack);

    // loop-invariant precomputation
    lift_kernel<<<N0, 128, 0, stream>>>(samples, lift_w, lift_b, v_down0, N0);
    matmul128_kernel<<<(N0 + 7) / 8, 128, 0, stream>>>(v_down0, W0_w, W0_b, w0term, N0);
    // gno00: x=lvl0 (sx=1), y=lvl0 (sy=1), f=v_down0
    gno_kernel<<<N0, 128, 0, stream>>>(coords, N0, 1, 1, v_down0,
        es[0], rp00, gw1[0], gb1[0], w2pack + 0 * 8192, gb2[0],
        nullptr, nullptr, 0, gno00o, nullptr, nullptr, nullptr);
    // gno01 base: x=lvl1 (sx=2), y=lvl0 (sy=1), f=v_down0
    gno_kernel<<<N1, 128, 0, stream>>>(coords, N0, 2, 1, v_down0,
        es[1], rp01, gw1[1], gb1[1], w2pack + 1 * 8192, gb2[1],
        nullptr, nullptr, 0, gno01b, nullptr, nullptr, nullptr);

    // 3 iterations of the coarse-level recursion
    for (int it = 0; it < 3; ++it) {
        // v_down1 = relu(gno01b [+ v_up1]); w1term = v_down1 @ W1 + b1  (fused)
        fused_relu_mm_kernel<<<(N1 + 7) / 8, 128, 0, stream>>>(
            gno01b, (it == 0) ? nullptr : v_up1, v_down1, W1_w, W1_b, w1term, N1);
        // gno11: v_up1 = relu(mean + w1term)
        gno_kernel<<<N1, 128, 0, stream>>>(coords, N0, 2, 2, v_down1,
            es[3], rp11, gw1[3], gb1[3], w2pack + 3 * 8192, gb2[3],
            w1term, nullptr, 1, v_up1, nullptr, nullptr, nullptr);
    }

    // final upward pass + fused projection:
    // v_up0 = relu(gno10_mean + w0term + gno00o); d_out = v_up0 @ proj_w + proj_b
    gno_kernel<<<N0, 128, 0, stream>>>(coords, N0, 1, 2, v_up1,
        es[2], rp10, gw1[2], gb1[2], w2pack + 2 * 8192, gb2[2],
        w0term, gno00o, 1, nullptr, proj_w, proj_b, (float*)d_out);
}